// Round 16
// baseline (440.483 us; speedup 1.0000x reference)
//
#include <hip/hip_runtime.h>

#define DEV __device__ __forceinline__

typedef unsigned short u16;
typedef __attribute__((ext_vector_type(8))) __bf16 bf16x8;
typedef __attribute__((ext_vector_type(4))) float f32x4;

// ---------- helpers ----------
DEV u16 f2b(float f) {                       // f32 -> bf16 bits, RNE
    unsigned u = __builtin_bit_cast(unsigned, f);
    unsigned r = u + 0x7fffu + ((u >> 16) & 1u);
    return (u16)(r >> 16);
}

DEV f32x4 mfma16(bf16x8 a, bf16x8 b, f32x4 c) {
    return __builtin_amdgcn_mfma_f32_16x16x32_bf16(a, b, c, 0, 0, 0);
}

#define GLOAD_LDS16(gp, lp)                                                       \
    __builtin_amdgcn_global_load_lds((__attribute__((address_space(1))) void*)(gp), \
                                     (__attribute__((address_space(3))) void*)(lp), \
                                     16, 0, 0)

// counted waits for ring-4 pipelines (L = loads/thread/stage)
template <int L>
DEV void wait_ring(int kt, int NT) {
    if (kt + 2 < NT) {
        if constexpr (L == 2) asm volatile("s_waitcnt vmcnt(4)" ::: "memory");
        if constexpr (L == 3) asm volatile("s_waitcnt vmcnt(6)" ::: "memory");
        if constexpr (L == 4) asm volatile("s_waitcnt vmcnt(8)" ::: "memory");
    } else if (kt + 1 < NT) {
        if constexpr (L == 2) asm volatile("s_waitcnt vmcnt(2)" ::: "memory");
        if constexpr (L == 3) asm volatile("s_waitcnt vmcnt(3)" ::: "memory");
        if constexpr (L == 4) asm volatile("s_waitcnt vmcnt(4)" ::: "memory");
    } else {
        asm volatile("s_waitcnt vmcnt(0)" ::: "memory");
    }
}

// ---------- fused embed (blocks [0,4096)) + 12-region cast (blocks >=4096) ----------
struct CastArgs {
    const float4* src[12];
    ushort4* dst[12];
    int start4[13];
    const int* tokens;
    const float* emb;
    float* xf;
    u16* xb;
};

__global__ __launch_bounds__(256) void cast_embed_k(CastArgs a) {
    const int bid = blockIdx.x;
    if (bid < 4096) {
        int i   = bid * 256 + threadIdx.x;
        int row = i >> 8;
        int dp  = i & 255;
        int pos = row & 1023;
        int tok = a.tokens[row];
        const float* e = a.emb + (size_t)tok * 512 + dp * 2;
        float e0 = e[0] * 22.627416997969522f;
        float e1 = e[1] * 22.627416997969522f;
        float freq = exp2f(-(float)dp * 0.05190512648262190f);
        float ang  = (float)pos * freq;
        float v0 = e0 + __sinf(ang);
        float v1 = e1 + __cosf(ang);
        size_t o = (size_t)row * 512 + dp * 2;
        a.xf[o] = v0; a.xf[o + 1] = v1;
        a.xb[o] = f2b(v0); a.xb[o + 1] = f2b(v1);
        return;
    }
    const int total = a.start4[12];
    const int nblk = gridDim.x - 4096;
    for (int i = (bid - 4096) * 256 + threadIdx.x; i < total; i += nblk * 256) {
        int j = 0;
#pragma unroll
        for (int t = 1; t < 12; t++) j += (i >= a.start4[t]) ? 1 : 0;
        const int loc = i - a.start4[j];
        float4 v = a.src[j][loc];
        ushort4 o;
        o.x = f2b(v.x); o.y = f2b(v.y); o.z = f2b(v.z); o.w = f2b(v.w);
        a.dst[j][loc] = o;
    }
}

// ---------- generic NT GEMM: ring-4 + counted vmcnt (small projections) ----------
template <int BM, int BN>
__global__ __launch_bounds__(256) void gemm_sm_k(const u16* __restrict__ A,
                                                 const u16* __restrict__ W,
                                                 const float* __restrict__ b0,
                                                 const float* __restrict__ b1,
                                                 const float* __restrict__ b2,
                                                 float* __restrict__ Cf,
                                                 u16* __restrict__ Cb,
                                                 int M, int N, int K, int relu) {
    constexpr int MF = BM / 32;
    constexpr int NF = BN / 32;
    constexpr int CH_A = BM * 4;
    constexpr int CH_TOT = (BM + BN) * 4;
    constexpr int L = CH_TOT / 256;
    __shared__ u16 sA[4][BM * 32];
    __shared__ u16 sB[4][BN * 32];

    const int gx = gridDim.x;
    const int nwg = gx * gridDim.y;
    const int orig = blockIdx.y * gx + blockIdx.x;
    const int xcd = orig & 7, chnk = orig >> 3;
    const int q = nwg >> 3, r = nwg & 7;
    const int wgid = (xcd < r ? xcd * (q + 1) : r * (q + 1) + (xcd - r) * q) + chnk;
    const int m0 = (wgid % gx) * BM;
    const int n0 = (wgid / gx) * BN;

    const int tid  = threadIdx.x;
    const int lane = tid & 63;
    const int wid  = tid >> 6;
    const int wr = wid >> 1, wc = wid & 1;
    const int lg = lane >> 4, lr = lane & 15;

    f32x4 acc[MF][NF];
#pragma unroll
    for (int i = 0; i < MF; i++)
#pragma unroll
        for (int j = 0; j < NF; j++) acc[i][j] = (f32x4){0.f, 0.f, 0.f, 0.f};

    auto stage = [&](int b, int kt) {
        const int k0 = kt << 5;
#pragma unroll
        for (int h = 0; h < L; h++) {
            const int c = tid + h * 256;
            if (c < CH_A) {
                const int row = c >> 2, ch = c & 3;
                const int gch = ch ^ ((row >> 1) & 3);
                GLOAD_LDS16(A + (size_t)(m0 + row) * K + k0 + gch * 8,
                            &sA[b][c * 8]);
            } else {
                const int cb = c - CH_A;
                const int row = cb >> 2, ch = cb & 3;
                const int gch = ch ^ ((row >> 1) & 3);
                GLOAD_LDS16(W + (size_t)(n0 + row) * K + k0 + gch * 8,
                            &sB[b][cb * 8]);
            }
        }
    };

    const int NT = K >> 5;
    stage(0, 0); stage(1, 1); stage(2, 2);

    for (int kt = 0; kt < NT; kt++) {
        wait_ring<L>(kt, NT);
        __builtin_amdgcn_s_barrier();
        const int bsel = kt & 3;
        if (kt + 3 < NT) stage((kt + 3) & 3, kt + 3);

        bf16x8 af[MF], bfr[NF];
#pragma unroll
        for (int mi = 0; mi < MF; mi++) {
            const int row = wr * (BM / 2) + mi * 16 + lr;
            af[mi] = *(const bf16x8*)(&sA[bsel][row * 32 + (lg ^ ((row >> 1) & 3)) * 8]);
        }
#pragma unroll
        for (int ni = 0; ni < NF; ni++) {
            const int row = wc * (BN / 2) + ni * 16 + lr;
            bfr[ni] = *(const bf16x8*)(&sB[bsel][row * 32 + (lg ^ ((row >> 1) & 3)) * 8]);
        }
        __builtin_amdgcn_s_setprio(1);
#pragma unroll
        for (int mi = 0; mi < MF; mi++)
#pragma unroll
            for (int ni = 0; ni < NF; ni++)
                acc[mi][ni] = mfma16(af[mi], bfr[ni], acc[mi][ni]);
        __builtin_amdgcn_s_setprio(0);
    }

#pragma unroll
    for (int mi = 0; mi < MF; mi++) {
        const int rbase = m0 + wr * (BM / 2) + mi * 16 + lg * 4;
#pragma unroll
        for (int ni = 0; ni < NF; ni++) {
            const int col = n0 + wc * (BN / 2) + ni * 16 + lr;
            const float* bp = b0; int cc = col;
            if (b1 && col >= 512)  { bp = b1; cc = col - 512; }
            if (b2 && col >= 1024) { bp = b2; cc = col - 1024; }
            const float bv = bp[cc];
#pragma unroll
            for (int rr = 0; rr < 4; rr++) {
                float v = acc[mi][ni][rr] + bv;
                if (relu) v = fmaxf(v, 0.f);
                if (Cf) Cf[(size_t)(rbase + rr) * N + col] = v;
                if (Cb) Cb[(size_t)(rbase + rr) * N + col] = f2b(v);
            }
        }
    }
}

// ---------- Wout GEMM: 128x64 tile, ring-3 (36 KB LDS -> 4 blocks/CU) WITH
// counted vmcnt(3); m-fast 1-D grid; full-line NT-store epilogue via LDS
// bounce (per-wave 64x32 f32 tile, 128 B = one full line per row). ----------
__global__ __launch_bounds__(256) void gemm_wout_k(const u16* __restrict__ A,
                                                   const u16* __restrict__ W,
                                                   const float* __restrict__ bias,
                                                   float* __restrict__ C,
                                                   int M, int N, int K) {
    __shared__ u16 sA[3][128 * 32];            // 3 x 8 KB
    __shared__ u16 sB[3][64 * 32];             // 3 x 4 KB  (total 36 KB)
    const int orig = blockIdx.x;               // nwg = 16000, %8 == 0
    const int wgid = (orig & 7) * 2000 + (orig >> 3);
    const int m0 = (wgid & 31) * 128;          // m-fast, 32 m-panels
    const int n0 = (wgid >> 5) * 64;           // 500 n-panels

    const int tid  = threadIdx.x;
    const int lane = tid & 63;
    const int wid  = tid >> 6;
    const int wr = wid >> 1, wc = wid & 1;     // per-wave out 64x32
    const int lg = lane >> 4, lr = lane & 15;

    f32x4 acc[4][2];
#pragma unroll
    for (int i = 0; i < 4; i++)
#pragma unroll
        for (int j = 0; j < 2; j++) acc[i][j] = (f32x4){0.f, 0.f, 0.f, 0.f};

    auto stage = [&](int b, int kt) {
        const int k0 = kt << 5;
#pragma unroll
        for (int h = 0; h < 3; h++) {          // 768 chunks: 512 A + 256 B
            const int c = tid + h * 256;
            if (c < 512) {
                const int row = c >> 2, ch = c & 3;
                const int gch = ch ^ ((row >> 1) & 3);
                GLOAD_LDS16(A + (size_t)(m0 + row) * K + k0 + gch * 8,
                            &sA[b][c * 8]);
            } else {
                const int cb = c - 512;
                const int row = cb >> 2, ch = cb & 3;
                const int gch = ch ^ ((row >> 1) & 3);
                GLOAD_LDS16(W + (size_t)(n0 + row) * K + k0 + gch * 8,
                            &sB[b][cb * 8]);
            }
        }
    };

    const int NT = K >> 5;                     // 16
    stage(0, 0); stage(1, 1);                  // 2 tiles ahead (ring-3)
    for (int kt = 0; kt < NT; kt++) {
        // oldest outstanding = tile kt (3 loads); keep kt+1's 3 in flight
        if (kt + 1 < NT) asm volatile("s_waitcnt vmcnt(3)" ::: "memory");
        else             asm volatile("s_waitcnt vmcnt(0)" ::: "memory");
        __builtin_amdgcn_s_barrier();
        const int bsel = kt % 3;
        // target (kt+2)%3 == (kt-1)%3: freed (reads consumed pre-barrier)
        if (kt + 2 < NT) stage((kt + 2) % 3, kt + 2);

        bf16x8 af[4], bfr[2];
#pragma unroll
        for (int mi = 0; mi < 4; mi++) {
            const int row = wr * 64 + mi * 16 + lr;
            af[mi] = *(const bf16x8*)(&sA[bsel][row * 32 + (lg ^ ((row >> 1) & 3)) * 8]);
        }
#pragma unroll
        for (int ni = 0; ni < 2; ni++) {
            const int row = wc * 32 + ni * 16 + lr;
            bfr[ni] = *(const bf16x8*)(&sB[bsel][row * 32 + (lg ^ ((row >> 1) & 3)) * 8]);
        }
        __builtin_amdgcn_s_setprio(1);
#pragma unroll
        for (int mi = 0; mi < 4; mi++)
#pragma unroll
            for (int ni = 0; ni < 2; ni++)
                acc[mi][ni] = mfma16(af[mi], bfr[ni], acc[mi][ni]);
        __builtin_amdgcn_s_setprio(0);
    }

    // ---- epilogue: per-wave LDS bounce -> full-line f32x4 NT stores ----
    __syncthreads();                            // staging LDS now reusable
    float* patch = (float*)(&sA[0][0]) + wid * (16 * 36);   // 2.25 KB/wave
    const int mrow_base = m0 + wr * 64;
    const int ncol_base = n0 + wc * 32;
#pragma unroll
    for (int mi = 0; mi < 4; mi++) {
#pragma unroll
        for (int ni = 0; ni < 2; ni++) {
            const float bv = bias[ncol_base + ni * 16 + lr];
#pragma unroll
            for (int rr = 0; rr < 4; rr++)
                patch[(lg * 4 + rr) * 36 + ni * 16 + lr] = acc[mi][ni][rr] + bv;
        }
        asm volatile("s_waitcnt lgkmcnt(0)" ::: "memory");
        __builtin_amdgcn_sched_barrier(0);
#pragma unroll
        for (int p = 0; p < 2; p++) {
            const int row = p * 8 + (lane >> 3);          // 8 rows/pass
            const int c4  = lane & 7;                     // 8 f32x4 = 128 B/row
            f32x4 v = *(const f32x4*)(&patch[row * 36 + c4 * 4]);
            __builtin_nontemporal_store(
                v, (f32x4*)&C[(size_t)(mrow_base + mi * 16 + row) * N +
                              ncol_base + c4 * 4]);
        }
        asm volatile("s_waitcnt lgkmcnt(0)" ::: "memory"); // reads done before overwrite
        __builtin_amdgcn_sched_barrier(0);
    }
}

// ---------- dual GEMM: z=0 QKV (N=1536), z=1 eKV (N=1024); BM=64,BN=128,K=512 ----------
struct DualArgs {
    const u16 *A0, *W0, *A1, *W1;
    const float *b00, *b01, *b02, *b10, *b11;
    u16 *C0, *C1;
};

__global__ __launch_bounds__(256) void gemm_dual_k(DualArgs da) {
    constexpr int BM = 64, BN = 128, MF = 2, NF = 4;
    constexpr int CH_A = BM * 4, CH_TOT = (BM + BN) * 4, L = CH_TOT / 256;
    __shared__ u16 sA[4][BM * 32];
    __shared__ u16 sB[4][BN * 32];

    const int z = blockIdx.z;
    const int gy = z ? 8 : 12;
    if ((int)blockIdx.y >= gy) return;
    const int N = z ? 1024 : 1536;
    const u16* A = z ? da.A1 : da.A0;
    const u16* W = z ? da.W1 : da.W0;
    u16* C = z ? da.C1 : da.C0;
    const int K = 512;

    const int gx = gridDim.x;                 // 64
    const int nwg = gx * gy;
    const int orig = blockIdx.y * gx + blockIdx.x;
    const int xcd = orig & 7, chnk = orig >> 3;
    const int q = nwg >> 3, r = nwg & 7;
    const int wgid = (xcd < r ? xcd * (q + 1) : r * (q + 1) + (xcd - r) * q) + chnk;
    const int m0 = (wgid % gx) * BM;
    const int n0 = (wgid / gx) * BN;

    const int tid  = threadIdx.x;
    const int lane = tid & 63;
    const int wid  = tid >> 6;
    const int wr = wid >> 1, wc = wid & 1;
    const int lg = lane >> 4, lr = lane & 15;

    f32x4 acc[MF][NF];
#pragma unroll
    for (int i = 0; i < MF; i++)
#pragma unroll
        for (int j = 0; j < NF; j++) acc[i][j] = (f32x4){0.f, 0.f, 0.f, 0.f};

    auto stage = [&](int b, int kt) {
        const int k0 = kt << 5;
#pragma unroll
        for (int h = 0; h < L; h++) {
            const int c = tid + h * 256;
            if (c < CH_A) {
                const int row = c >> 2, ch = c & 3;
                const int gch = ch ^ ((row >> 1) & 3);
                GLOAD_LDS16(A + (size_t)(m0 + row) * K + k0 + gch * 8,
                            &sA[b][c * 8]);
            } else {
                const int cb = c - CH_A;
                const int row = cb >> 2, ch = cb & 3;
                const int gch = ch ^ ((row >> 1) & 3);
                GLOAD_LDS16(W + (size_t)(n0 + row) * K + k0 + gch * 8,
                            &sB[b][cb * 8]);
            }
        }
    };

    const int NT = K >> 5;                    // 16
    stage(0, 0); stage(1, 1); stage(2, 2);

    for (int kt = 0; kt < NT; kt++) {
        wait_ring<L>(kt, NT);
        __builtin_amdgcn_s_barrier();
        const int bsel = kt & 3;
        if (kt + 3 < NT) stage((kt + 3) & 3, kt + 3);

        bf16x8 af[MF], bfr[NF];
#pragma unroll
        for (int mi = 0; mi < MF; mi++) {
            const int row = wr * (BM / 2) + mi * 16 + lr;
            af[mi] = *(const bf16x8*)(&sA[bsel][row * 32 + (lg ^ ((row >> 1) & 3)) * 8]);
        }
#pragma unroll
        for (int ni = 0; ni < NF; ni++) {
            const int row = wc * (BN / 2) + ni * 16 + lr;
            bfr[ni] = *(const bf16x8*)(&sB[bsel][row * 32 + (lg ^ ((row >> 1) & 3)) * 8]);
        }
        __builtin_amdgcn_s_setprio(1);
#pragma unroll
        for (int mi = 0; mi < MF; mi++)
#pragma unroll
            for (int ni = 0; ni < NF; ni++)
                acc[mi][ni] = mfma16(af[mi], bfr[ni], acc[mi][ni]);
        __builtin_amdgcn_s_setprio(0);
    }

#pragma unroll
    for (int mi = 0; mi < MF; mi++) {
        const int rbase = m0 + wr * (BM / 2) + mi * 16 + lg * 4;
#pragma unroll
        for (int ni = 0; ni < NF; ni++) {
            const int col = n0 + wc * (BN / 2) + ni * 16 + lr;
            const float* bp; int cc;
            if (z == 0) {
                if (col >= 1024)     { bp = da.b02; cc = col - 1024; }
                else if (col >= 512) { bp = da.b01; cc = col - 512; }
                else                 { bp = da.b00; cc = col; }
            } else {
                if (col >= 512)      { bp = da.b11; cc = col - 512; }
                else                 { bp = da.b10; cc = col; }
            }
            const float bv = bp[cc];
#pragma unroll
            for (int rr = 0; rr < 4; rr++)
                C[(size_t)(rbase + rr) * N + col] = f2b(acc[mi][ni][rr] + bv);
        }
    }
}

// ---------- V transpose (both attns in one launch): z selects src ----------
__global__ __launch_bounds__(256) void vt_k(const u16* __restrict__ V0, int rs0,
                                            u16* __restrict__ VT0,
                                            const u16* __restrict__ V1, int rs1,
                                            u16* __restrict__ VT1) {
    const u16* V = blockIdx.z ? V1 : V0;
    u16* VT = blockIdx.z ? VT1 : VT0;
    const int rs = blockIdx.z ? rs1 : rs0;
    const int bh = blockIdx.x;
    const int b = bh >> 3;
    const int h64 = (bh & 7) * 64;
    const int t0 = blockIdx.y * 64;
    __shared__ u16 s[64 * 65];
    const int tid = threadIdx.x;
#pragma unroll
    for (int i = 0; i < 16; i++) {
        int t = (tid >> 6) + i * 4;
        int d = tid & 63;
        s[d * 65 + t] = V[(size_t)(b * 1024 + t0 + t) * rs + h64 + d];
    }
    __syncthreads();
#pragma unroll
    for (int i = 0; i < 16; i++) {
        int d = (tid >> 6) + i * 4;
        int t = tid & 63;
        VT[(size_t)(bh * 64 + d) * 1024 + t0 + t] = s[d * 65 + t];
    }
}

// ---------- flash attention: 4-wave blocks (64 q-rows), K/V staged to LDS
// via global_load_lds double-buffer (ring-2), XOR-swizzled both sides. ----------
template <int CAUSAL>
__global__ __launch_bounds__(256) void attn_k(const u16* __restrict__ Q, int qrs,
                                              const u16* __restrict__ Kb, int krs,
                                              const u16* __restrict__ VT,
                                              const int* __restrict__ tokens,
                                              const signed char* __restrict__ km8,
                                              u16* __restrict__ O, int LK) {
    const int bh = blockIdx.x;
    const int b = bh >> 3;
    const int h64 = (bh & 7) * 64;
    const int qblk = blockIdx.y;               // 64 q-rows per block
    const int tid = threadIdx.x;
    const int wid = tid >> 6;
    const int lane = tid & 63;
    const int lg = lane >> 4, lr = lane & 15;
    const float NEG = -3.402823466e38f;

    __shared__ u16 sK[2][64 * 64];             // [key][d], chunk-swizzled
    __shared__ u16 sV[2][64 * 64];             // [d][key], chunk-swizzled
    __shared__ u16 sP[4][16 * 72];             // per-wave P exchange
    __shared__ int sFlag;

    const int q0 = qblk * 64 + wid * 16;
    const u16* qrow = Q + (size_t)(b * 1024 + q0 + lr) * qrs + h64 + lg * 8;
    const bf16x8 aq0 = *(const bf16x8*)(qrow);
    const bf16x8 aq1 = *(const bf16x8*)(qrow + 32);

    f32x4 o[4];
#pragma unroll
    for (int ni = 0; ni < 4; ni++) o[ni] = (f32x4){0.f, 0.f, 0.f, 0.f};
    float m_run[4], l_run[4];
#pragma unroll
    for (int rr = 0; rr < 4; rr++) { m_run[rr] = NEG; l_run[rr] = 0.f; }

    const u16* kbase = Kb + (size_t)b * LK * krs + h64;
    const u16* vbase = VT + (size_t)bh * 64 * LK;

    auto stage = [&](int buf, int k0) {
#pragma unroll
        for (int h = 0; h < 2; h++) {
            const int cidx = tid + h * 256;    // 512 chunks of 16B (K tile)
            const int rk = cidx >> 3, ch = cidx & 7;
            GLOAD_LDS16(kbase + (size_t)(k0 + rk) * krs + (ch ^ (rk & 7)) * 8,
                        &sK[buf][cidx * 8]);
        }
#pragma unroll
        for (int h = 0; h < 2; h++) {
            const int cidx = tid + h * 256;    // 512 chunks (V tile)
            const int dv = cidx >> 3, ch = cidx & 7;
            GLOAD_LDS16(vbase + (size_t)dv * LK + k0 + (ch ^ (dv & 7)) * 8,
                        &sV[buf][cidx * 8]);
        }
    };

    auto body = [&](int cur, int k0) {
        f32x4 s[4];
        __builtin_amdgcn_s_setprio(1);
#pragma unroll
        for (int c = 0; c < 4; c++) {
            const int rk = c * 16 + lr;
            bf16x8 bk0 = *(const bf16x8*)(&sK[cur][(rk * 8 + (lg ^ (rk & 7))) * 8]);
            bf16x8 bk1 =
                *(const bf16x8*)(&sK[cur][(rk * 8 + ((lg + 4) ^ (rk & 7))) * 8]);
            f32x4 t = (f32x4){0.f, 0.f, 0.f, 0.f};
            t = mfma16(aq0, bk0, t);
            t = mfma16(aq1, bk1, t);
            s[c] = t;
        }
        __builtin_amdgcn_s_setprio(0);
#pragma unroll
        for (int c = 0; c < 4; c++) {
            const int key = k0 + c * 16 + lr;
            bool mkey;
            if (CAUSAL) mkey = (tokens[b * LK + key] == 0);
            else        mkey = (km8[b * LK + key] != 0);
#pragma unroll
            for (int rr = 0; rr < 4; rr++) {
                float sv = s[c][rr] * 0.125f;   // 1/sqrt(64)
                bool mk = mkey;
                if (CAUSAL) mk = mk || (key > q0 + lg * 4 + rr);
                s[c][rr] = mk ? NEG : sv;
            }
        }
        float pf[4];
#pragma unroll
        for (int rr = 0; rr < 4; rr++) {
            float bm = fmaxf(fmaxf(s[0][rr], s[1][rr]), fmaxf(s[2][rr], s[3][rr]));
            bm = fmaxf(bm, __shfl_xor(bm, 1));
            bm = fmaxf(bm, __shfl_xor(bm, 2));
            bm = fmaxf(bm, __shfl_xor(bm, 4));
            bm = fmaxf(bm, __shfl_xor(bm, 8));
            float mn = fmaxf(m_run[rr], bm);
            float sc = __expf(m_run[rr] - mn);
            float p0 = __expf(s[0][rr] - mn);
            float p1 = __expf(s[1][rr] - mn);
            float p2 = __expf(s[2][rr] - mn);
            float p3 = __expf(s[3][rr] - mn);
            float bs = (p0 + p1) + (p2 + p3);
            bs += __shfl_xor(bs, 1);
            bs += __shfl_xor(bs, 2);
            bs += __shfl_xor(bs, 4);
            bs += __shfl_xor(bs, 8);
            l_run[rr] = l_run[rr] * sc + bs;
            m_run[rr] = mn;
            pf[rr] = sc;
            s[0][rr] = p0; s[1][rr] = p1; s[2][rr] = p2; s[3][rr] = p3;
        }
#pragma unroll
        for (int ni = 0; ni < 4; ni++)
#pragma unroll
            for (int rr = 0; rr < 4; rr++) o[ni][rr] *= pf[rr];
#pragma unroll
        for (int c = 0; c < 4; c++)
#pragma unroll
            for (int rr = 0; rr < 4; rr++)
                sP[wid][(lg * 4 + rr) * 72 + c * 16 + lr] = f2b(s[c][rr]);
        bf16x8 ap0 = *(const bf16x8*)(&sP[wid][lr * 72 + lg * 8]);
        bf16x8 ap1 = *(const bf16x8*)(&sP[wid][lr * 72 + 32 + lg * 8]);
        __builtin_amdgcn_s_setprio(1);
#pragma unroll
        for (int ni = 0; ni < 4; ni++) {
            const int rv = ni * 16 + lr;
            bf16x8 bv0 = *(const bf16x8*)(&sV[cur][(rv * 8 + (lg ^ (rv & 7))) * 8]);
            bf16x8 bv1 =
                *(const bf16x8*)(&sV[cur][(rv * 8 + ((lg + 4) ^ (rv & 7))) * 8]);
            o[ni] = mfma16(ap0, bv0, o[ni]);
            o[ni] = mfma16(ap1, bv1, o[ni]);
        }
        __builtin_amdgcn_s_setprio(0);
    };

    int kend = CAUSAL ? ((qblk + 1) << 6) : LK;
    if (kend > LK) kend = LK;
    const int nit = kend >> 6;
    stage(0, 0);
    for (int it = 0; it < nit; it++) {
        asm volatile("s_waitcnt vmcnt(0)" ::: "memory");
        __syncthreads();
        const int cur = it & 1;
        if (it + 1 < nit) stage(cur ^ 1, (it + 1) << 6);
        body(cur, it << 6);
    }
    if (CAUSAL && kend < LK) {
        bool fm = (m_run[0] == NEG) || (m_run[1] == NEG) ||
                  (m_run[2] == NEG) || (m_run[3] == NEG);
        if (tid == 0) sFlag = 0;
        __syncthreads();
        if (__any(fm) && lane == 0) sFlag = 1;
        __syncthreads();
        if (sFlag) {
            const int nit2 = LK >> 6;
            stage(nit & 1, nit << 6);
            for (int it = nit; it < nit2; it++) {
                asm volatile("s_waitcnt vmcnt(0)" ::: "memory");
                __syncthreads();
                const int cur = it & 1;
                if (it + 1 < nit2) stage(cur ^ 1, (it + 1) << 6);
                body(cur, it << 6);
            }
        }
    }

#pragma unroll
    for (int ni = 0; ni < 4; ni++)
#pragma unroll
        for (int rr = 0; rr < 4; rr++) {
            float v = o[ni][rr] / l_run[rr];
            O[(size_t)(b * 1024 + q0 + lg * 4 + rr) * 512 + h64 + ni * 16 + lr] =
                f2b(v);
        }
}

// ---------- fused residual + LayerNorm; writes f32 (opt) + bf16 ----------
__global__ __launch_bounds__(256) void ln_k(const float* __restrict__ a,
                                            const float* __restrict__ res,
                                            const float* __restrict__ g,
                                            const float* __restrict__ be,
                                            float* __restrict__ outf,
                                            u16* __restrict__ outb) {
    const int row = blockIdx.x;
    const int tid = threadIdx.x;
    const size_t base = (size_t)row * 512;
    float2 av = ((const float2*)(a + base))[tid];
    float2 rv = ((const float2*)(res + base))[tid];
    float x0 = av.x + rv.x;
    float x1 = av.y + rv.y;
    float s = x0 + x1, q = x0 * x0 + x1 * x1;
#pragma unroll
    for (int off = 1; off < 64; off <<= 1) {
        s += __shfl_xor(s, off);
        q += __shfl_xor(q, off);
    }
    __shared__ float ps[8];
    const int wid = tid >> 6;
    if ((tid & 63) == 0) { ps[wid] = s; ps[wid + 4] = q; }
    __syncthreads();
    s = ps[0] + ps[1] + ps[2] + ps[3];
    q = ps[4] + ps[5] + ps[6] + ps[7];
    const float mu = s * (1.f / 512.f);
    const float var = q * (1.f / 512.f) - mu * mu;
    const float inv = rsqrtf(var + 1e-5f);
    float2 gv = ((const float2*)g)[tid];
    float2 bv = ((const float2*)be)[tid];
    float y0 = gv.x * (x0 - mu) * inv + bv.x;
    float y1 = gv.y * (x1 - mu) * inv + bv.y;
    if (outf) { ((float2*)(outf + base))[tid] = make_float2(y0, y1); }
    outb[base + tid * 2] = f2b(y0);
    outb[base + tid * 2 + 1] = f2b(y1);
}

// ---------- host ----------
extern "C" void kernel_launch(void* const* d_in, const int* in_sizes, int n_in,
                              void* d_out, int out_size, void* d_ws, size_t ws_size,
                              hipStream_t stream) {
    (void)in_sizes; (void)n_in; (void)out_size;
    const int*   tokens  = (const int*)d_in[0];
    const float* enc     = (const float*)d_in[1];
    const signed char* encmask = (const signed char*)d_in[2];
    const float* emb     = (const float*)d_in[3];
    const float* Wq  = (const float*)d_in[4];  const float* bq  = (const float*)d_in[5];
    const float* Wk  = (const float*)d_in[6];  const float* bk  = (const float*)d_in[7];
    const float* Wv  = (const float*)d_in[8];  const float* bv  = (const float*)d_in[9];
    const float* Wo1 = (const float*)d_in[10]; const float* bo1 = (const float*)d_in[11];
    const float* cWq = (const float*)d_in[12]; const float* cbq = (const float*)d_in[13];
    const float* eWk = (const float*)d_in[14]; const float* ebk = (const float*)d_in[15];
    const float* eWv = (const float*)d_in[16]; const float* ebv = (const float*)d_in[17];
    const float* Wo2 = (const float*)d_in[18]; const float* bo2 = (const float*)d_in[19];
    const float* W1  = (const float*)d_in[20]; const float* b1  = (const float*)d_in[21];
    const float* W2  = (const float*)d_in[22]; const float* b2  = (const float*)d_in[23];
    const float* g1  = (const float*)d_in[24]; const float* be1 = (const float*)d_in[25];
    const float* g2  = (const float*)d_in[26]; const float* be2 = (const float*)d_in[27];
    const float* g3  = (const float*)d_in[28]; const float* be3 = (const float*)d_in[29];
    const float* Wout= (const float*)d_in[30]; const float* bout= (const float*)d_in[31];
    float* out = (float*)d_out;

    char* ws = (char*)d_ws;
    size_t off = 0;
    auto alloc = [&](size_t bytes) -> void* {
        void* p = ws + off;
        off += (bytes + 255) & ~(size_t)255;
        return p;
    };

    u16* Wqkvb = (u16*)alloc((size_t)786432 * 2);        // [1536,512]
    u16* Wo1b  = (u16*)alloc(262144 * 2);
    u16* cWqb  = (u16*)alloc(262144 * 2);
    u16* eWkvb = (u16*)alloc((size_t)524288 * 2);        // [1024,512]
    u16* Wo2b  = (u16*)alloc(262144 * 2);
    u16* W1b   = (u16*)alloc(524288 * 2);
    u16* W2b   = (u16*)alloc(524288 * 2);
    u16* Woutb = (u16*)alloc((size_t)16384000 * 2);
    u16* encb  = (u16*)alloc((size_t)2097152 * 2);
    float* x0f = (float*)alloc((size_t)2097152 * 4);
    u16*   x0b = (u16*)alloc((size_t)2097152 * 2);
    float* x1f = (float*)alloc((size_t)2097152 * 4);
    u16*   x1b = (u16*)alloc((size_t)2097152 * 2);
    float* x2f = (float*)alloc((size_t)2097152 * 4);
    u16*   x2b = (u16*)alloc((size_t)2097152 * 2);
    u16*   x3b = (u16*)alloc((size_t)2097152 * 2);
    u16* qkv = (u16*)alloc((size_t)4096 * 1536 * 2);     // fused q|k|v
    u16* ekv = (u16*)alloc((size_t)4096 * 1024 * 2);     // fused ek|ev
    u16* cq  = (u16*)alloc((size_t)2097152 * 2);
    u16* vt  = (u16*)alloc((size_t)2097152 * 2);         // self-attn VT
    u16* vt2 = (u16*)alloc((size_t)2097152 * 2);         // cross-attn VT
    u16* t4  = (u16*)alloc((size_t)2097152 * 2);         // attn out (reused)
    float* p8 = (float*)alloc((size_t)2097152 * 4);
    u16*  hb  = (u16*)alloc((size_t)4194304 * 2);        // relu hidden [4096,1024]
    if (off > ws_size) return;

    // fused embed + merged weight/enc casts (one launch)
    CastArgs ca;
    const float* srcs[12] = {Wq, Wk, Wv, Wo1, cWq, eWk, eWv, Wo2, W1, W2, enc, Wout};
    u16* dsts[12] = {Wqkvb, Wqkvb + 262144, Wqkvb + 524288, Wo1b, cWqb,
                     eWkvb, eWkvb + 262144, Wo2b, W1b, W2b, encb, Woutb};
    int ns[12] = {262144, 262144, 262144, 262144, 262144, 262144, 262144, 262144,
                  524288, 524288, 2097152, 16384000};
    int acc4 = 0;
    for (int j = 0; j < 12; j++) {
        ca.src[j] = (const float4*)srcs[j];
        ca.dst[j] = (ushort4*)dsts[j];
        ca.start4[j] = acc4;
        acc4 += ns[j] / 4;
    }
    ca.start4[12] = acc4;
    ca.tokens = tokens; ca.emb = emb; ca.xf = x0f; ca.xb = x0b;
    cast_embed_k<<<4096 + 2048, 256, 0, stream>>>(ca);

    // fused QKV (x0b) + eKV (encb) in ONE launch
    DualArgs da;
    da.A0 = x0b;  da.W0 = Wqkvb; da.A1 = encb; da.W1 = eWkvb;
    da.b00 = bq;  da.b01 = bk;   da.b02 = bv;
    da.b10 = ebk; da.b11 = ebv;
    da.C0 = qkv;  da.C1 = ekv;
    gemm_dual_k<<<dim3(64, 12, 2), 256, 0, stream>>>(da);

    // both V transposes, one launch
    vt_k<<<dim3(32, 16, 2), 256, 0, stream>>>(qkv + 1024, 1536, vt,
                                              ekv + 512, 1024, vt2);

    attn_k<1><<<dim3(32, 16), 256, 0, stream>>>(qkv, 1536, qkv + 512, 1536, vt,
                                                tokens, nullptr, t4, 1024);
    gemm_sm_k<64, 64><<<dim3(64, 8), 256, 0, stream>>>(
        t4, Wo1b, bo1, nullptr, nullptr, p8, nullptr, 4096, 512, 512, 0);
    ln_k<<<4096, 256, 0, stream>>>(p8, x0f, g1, be1, x1f, x1b);

    gemm_sm_k<64, 64><<<dim3(64, 8), 256, 0, stream>>>(
        x1b, cWqb, cbq, nullptr, nullptr, nullptr, cq, 4096, 512, 512, 0);
    attn_k<0><<<dim3(32, 16), 256, 0, stream>>>(cq, 512, ekv, 1024, vt2,
                                                nullptr, encmask, t4, 1024);
    gemm_sm_k<64, 64><<<dim3(64, 8), 256, 0, stream>>>(
        t4, Wo2b, bo2, nullptr, nullptr, p8, nullptr, 4096, 512, 512, 0);
    ln_k<<<4096, 256, 0, stream>>>(p8, x1f, g3, be3, x2f, x2b);

    // FFN
    gemm_sm_k<64, 128><<<dim3(64, 8), 256, 0, stream>>>(
        x2b, W1b, b1, nullptr, nullptr, nullptr, hb, 4096, 1024, 512, 1);
    gemm_sm_k<64, 64><<<dim3(64, 8), 256, 0, stream>>>(
        hb, W2b, b2, nullptr, nullptr, p8, nullptr, 4096, 512, 1024, 0);
    ln_k<<<4096, 256, 0, stream>>>(p8, x2f, g2, be2, nullptr, x3b);

    // vocab projection: 128x64 ring-3 counted-vmcnt (4 blocks/CU), m-fast grid,
    // full-line NT-store epilogue
    gemm_wout_k<<<16000, 256, 0, stream>>>(x3b, Woutb, bout, out, 4096, 32000, 512);
}

// Round 17
// 395.232 us; speedup vs baseline: 1.1145x; 1.1145x over previous
//
#include <hip/hip_runtime.h>

#define DEV __device__ __forceinline__

typedef unsigned short u16;
typedef __attribute__((ext_vector_type(8))) __bf16 bf16x8;
typedef __attribute__((ext_vector_type(4))) float f32x4;

// ---------- helpers ----------
DEV u16 f2b(float f) {                       // f32 -> bf16 bits, RNE
    unsigned u = __builtin_bit_cast(unsigned, f);
    unsigned r = u + 0x7fffu + ((u >> 16) & 1u);
    return (u16)(r >> 16);
}

DEV f32x4 mfma16(bf16x8 a, bf16x8 b, f32x4 c) {
    return __builtin_amdgcn_mfma_f32_16x16x32_bf16(a, b, c, 0, 0, 0);
}

#define GLOAD_LDS16(gp, lp)                                                       \
    __builtin_amdgcn_global_load_lds((__attribute__((address_space(1))) void*)(gp), \
                                     (__attribute__((address_space(3))) void*)(lp), \
                                     16, 0, 0)

// counted waits for ring-4 pipelines (L = loads/thread/stage)
template <int L>
DEV void wait_ring(int kt, int NT) {
    if (kt + 2 < NT) {
        if constexpr (L == 2) asm volatile("s_waitcnt vmcnt(4)" ::: "memory");
        if constexpr (L == 3) asm volatile("s_waitcnt vmcnt(6)" ::: "memory");
        if constexpr (L == 4) asm volatile("s_waitcnt vmcnt(8)" ::: "memory");
    } else if (kt + 1 < NT) {
        if constexpr (L == 2) asm volatile("s_waitcnt vmcnt(2)" ::: "memory");
        if constexpr (L == 3) asm volatile("s_waitcnt vmcnt(3)" ::: "memory");
        if constexpr (L == 4) asm volatile("s_waitcnt vmcnt(4)" ::: "memory");
    } else {
        asm volatile("s_waitcnt vmcnt(0)" ::: "memory");
    }
}

// ---------- fused embed (blocks [0,4096)) + 12-region cast (blocks >=4096) ----------
struct CastArgs {
    const float4* src[12];
    ushort4* dst[12];
    int start4[13];
    const int* tokens;
    const float* emb;
    float* xf;
    u16* xb;
};

__global__ __launch_bounds__(256) void cast_embed_k(CastArgs a) {
    const int bid = blockIdx.x;
    if (bid < 4096) {
        int i   = bid * 256 + threadIdx.x;
        int row = i >> 8;
        int dp  = i & 255;
        int pos = row & 1023;
        int tok = a.tokens[row];
        const float* e = a.emb + (size_t)tok * 512 + dp * 2;
        float e0 = e[0] * 22.627416997969522f;
        float e1 = e[1] * 22.627416997969522f;
        float freq = exp2f(-(float)dp * 0.05190512648262190f);
        float ang  = (float)pos * freq;
        float v0 = e0 + __sinf(ang);
        float v1 = e1 + __cosf(ang);
        size_t o = (size_t)row * 512 + dp * 2;
        a.xf[o] = v0; a.xf[o + 1] = v1;
        a.xb[o] = f2b(v0); a.xb[o + 1] = f2b(v1);
        return;
    }
    const int total = a.start4[12];
    const int nblk = gridDim.x - 4096;
    for (int i = (bid - 4096) * 256 + threadIdx.x; i < total; i += nblk * 256) {
        int j = 0;
#pragma unroll
        for (int t = 1; t < 12; t++) j += (i >= a.start4[t]) ? 1 : 0;
        const int loc = i - a.start4[j];
        float4 v = a.src[j][loc];
        ushort4 o;
        o.x = f2b(v.x); o.y = f2b(v.y); o.z = f2b(v.z); o.w = f2b(v.w);
        a.dst[j][loc] = o;
    }
}

// ---------- generic NT GEMM: ring-4 + counted vmcnt (small projections) ----------
template <int BM, int BN>
__global__ __launch_bounds__(256) void gemm_sm_k(const u16* __restrict__ A,
                                                 const u16* __restrict__ W,
                                                 const float* __restrict__ b0,
                                                 const float* __restrict__ b1,
                                                 const float* __restrict__ b2,
                                                 float* __restrict__ Cf,
                                                 u16* __restrict__ Cb,
                                                 int M, int N, int K, int relu) {
    constexpr int MF = BM / 32;
    constexpr int NF = BN / 32;
    constexpr int CH_A = BM * 4;
    constexpr int CH_TOT = (BM + BN) * 4;
    constexpr int L = CH_TOT / 256;
    __shared__ u16 sA[4][BM * 32];
    __shared__ u16 sB[4][BN * 32];

    const int gx = gridDim.x;
    const int nwg = gx * gridDim.y;
    const int orig = blockIdx.y * gx + blockIdx.x;
    const int xcd = orig & 7, chnk = orig >> 3;
    const int q = nwg >> 3, r = nwg & 7;
    const int wgid = (xcd < r ? xcd * (q + 1) : r * (q + 1) + (xcd - r) * q) + chnk;
    const int m0 = (wgid % gx) * BM;
    const int n0 = (wgid / gx) * BN;

    const int tid  = threadIdx.x;
    const int lane = tid & 63;
    const int wid  = tid >> 6;
    const int wr = wid >> 1, wc = wid & 1;
    const int lg = lane >> 4, lr = lane & 15;

    f32x4 acc[MF][NF];
#pragma unroll
    for (int i = 0; i < MF; i++)
#pragma unroll
        for (int j = 0; j < NF; j++) acc[i][j] = (f32x4){0.f, 0.f, 0.f, 0.f};

    auto stage = [&](int b, int kt) {
        const int k0 = kt << 5;
#pragma unroll
        for (int h = 0; h < L; h++) {
            const int c = tid + h * 256;
            if (c < CH_A) {
                const int row = c >> 2, ch = c & 3;
                const int gch = ch ^ ((row >> 1) & 3);
                GLOAD_LDS16(A + (size_t)(m0 + row) * K + k0 + gch * 8,
                            &sA[b][c * 8]);
            } else {
                const int cb = c - CH_A;
                const int row = cb >> 2, ch = cb & 3;
                const int gch = ch ^ ((row >> 1) & 3);
                GLOAD_LDS16(W + (size_t)(n0 + row) * K + k0 + gch * 8,
                            &sB[b][cb * 8]);
            }
        }
    };

    const int NT = K >> 5;
    stage(0, 0); stage(1, 1); stage(2, 2);

    for (int kt = 0; kt < NT; kt++) {
        wait_ring<L>(kt, NT);
        __builtin_amdgcn_s_barrier();
        const int bsel = kt & 3;
        if (kt + 3 < NT) stage((kt + 3) & 3, kt + 3);

        bf16x8 af[MF], bfr[NF];
#pragma unroll
        for (int mi = 0; mi < MF; mi++) {
            const int row = wr * (BM / 2) + mi * 16 + lr;
            af[mi] = *(const bf16x8*)(&sA[bsel][row * 32 + (lg ^ ((row >> 1) & 3)) * 8]);
        }
#pragma unroll
        for (int ni = 0; ni < NF; ni++) {
            const int row = wc * (BN / 2) + ni * 16 + lr;
            bfr[ni] = *(const bf16x8*)(&sB[bsel][row * 32 + (lg ^ ((row >> 1) & 3)) * 8]);
        }
        __builtin_amdgcn_s_setprio(1);
#pragma unroll
        for (int mi = 0; mi < MF; mi++)
#pragma unroll
            for (int ni = 0; ni < NF; ni++)
                acc[mi][ni] = mfma16(af[mi], bfr[ni], acc[mi][ni]);
        __builtin_amdgcn_s_setprio(0);
    }

#pragma unroll
    for (int mi = 0; mi < MF; mi++) {
        const int rbase = m0 + wr * (BM / 2) + mi * 16 + lg * 4;
#pragma unroll
        for (int ni = 0; ni < NF; ni++) {
            const int col = n0 + wc * (BN / 2) + ni * 16 + lr;
            const float* bp = b0; int cc = col;
            if (b1 && col >= 512)  { bp = b1; cc = col - 512; }
            if (b2 && col >= 1024) { bp = b2; cc = col - 1024; }
            const float bv = bp[cc];
#pragma unroll
            for (int rr = 0; rr < 4; rr++) {
                float v = acc[mi][ni][rr] + bv;
                if (relu) v = fmaxf(v, 0.f);
                if (Cf) Cf[(size_t)(rbase + rr) * N + col] = v;
                if (Cb) Cb[(size_t)(rbase + rr) * N + col] = f2b(v);
            }
        }
    }
}

// ---------- Wout GEMM: 128x128 ring-2 (32 KB LDS, 4 blocks/CU), 1-D grid,
// m-fast XCD mapping; epilogue bounces each wave's 64x64 f32 tile through a
// private LDS patch so NT stores emit full 128-B lines (256 B/row/inst). ----------
__global__ __launch_bounds__(256) void gemm_wout_k(const u16* __restrict__ A,
                                                   const u16* __restrict__ W,
                                                   const float* __restrict__ bias,
                                                   float* __restrict__ C,
                                                   int M, int N, int K) {
    __shared__ u16 sA[2][128 * 32];
    __shared__ u16 sB[2][128 * 32];
    const int orig = blockIdx.x;               // nwg = 8000, %8 == 0
    const int wgid = (orig & 7) * 1000 + (orig >> 3);
    const int m0 = (wgid & 31) * 128;          // m-fast
    const int n0 = (wgid >> 5) * 128;

    const int tid  = threadIdx.x;
    const int lane = tid & 63;
    const int wid  = tid >> 6;
    const int wr = wid >> 1, wc = wid & 1;
    const int lg = lane >> 4, lr = lane & 15;

    f32x4 acc[4][4];
#pragma unroll
    for (int i = 0; i < 4; i++)
#pragma unroll
        for (int j = 0; j < 4; j++) acc[i][j] = (f32x4){0.f, 0.f, 0.f, 0.f};

    auto stage = [&](int b, int kt) {
        const int k0 = kt << 5;
#pragma unroll
        for (int h = 0; h < 4; h++) {
            const int c = tid + h * 256;
            if (c < 512) {
                const int row = c >> 2, ch = c & 3;
                const int gch = ch ^ ((row >> 1) & 3);
                GLOAD_LDS16(A + (size_t)(m0 + row) * K + k0 + gch * 8,
                            &sA[b][c * 8]);
            } else {
                const int cb = c - 512;
                const int row = cb >> 2, ch = cb & 3;
                const int gch = ch ^ ((row >> 1) & 3);
                GLOAD_LDS16(W + (size_t)(n0 + row) * K + k0 + gch * 8,
                            &sB[b][cb * 8]);
            }
        }
    };

    const int NT = K >> 5;                     // 16
    stage(0, 0);
    for (int kt = 0; kt < NT; kt++) {
        asm volatile("s_waitcnt vmcnt(0)" ::: "memory");
        __builtin_amdgcn_s_barrier();          // tile kt in LDS; buf kt-1 free
        const int bsel = kt & 1;
        if (kt + 1 < NT) stage(bsel ^ 1, kt + 1);

        bf16x8 af[4], bfr[4];
#pragma unroll
        for (int mi = 0; mi < 4; mi++) {
            const int row = wr * 64 + mi * 16 + lr;
            af[mi] = *(const bf16x8*)(&sA[bsel][row * 32 + (lg ^ ((row >> 1) & 3)) * 8]);
        }
#pragma unroll
        for (int ni = 0; ni < 4; ni++) {
            const int row = wc * 64 + ni * 16 + lr;
            bfr[ni] = *(const bf16x8*)(&sB[bsel][row * 32 + (lg ^ ((row >> 1) & 3)) * 8]);
        }
        __builtin_amdgcn_s_setprio(1);
#pragma unroll
        for (int mi = 0; mi < 4; mi++)
#pragma unroll
            for (int ni = 0; ni < 4; ni++)
                acc[mi][ni] = mfma16(af[mi], bfr[ni], acc[mi][ni]);
        __builtin_amdgcn_s_setprio(0);
    }

    // ---- epilogue: per-wave LDS bounce -> full-line f32x4 NT stores ----
    __syncthreads();                            // staging LDS now reusable
    float* patch = (float*)(&sA[0][0]) + wid * (16 * 68);   // 4.25 KB/wave
    const int mrow_base = m0 + wr * 64;
    const int ncol_base = n0 + wc * 64;
#pragma unroll
    for (int mi = 0; mi < 4; mi++) {
#pragma unroll
        for (int ni = 0; ni < 4; ni++) {
            const float bv = bias[ncol_base + ni * 16 + lr];
#pragma unroll
            for (int rr = 0; rr < 4; rr++)
                patch[(lg * 4 + rr) * 68 + ni * 16 + lr] = acc[mi][ni][rr] + bv;
        }
        asm volatile("s_waitcnt lgkmcnt(0)" ::: "memory");
        __builtin_amdgcn_sched_barrier(0);
#pragma unroll
        for (int p = 0; p < 4; p++) {
            const int row = p * 4 + (lane >> 4);          // 4 rows/pass
            const int c4  = lane & 15;                    // 16 f32x4 = 256 B/row
            f32x4 v = *(const f32x4*)(&patch[row * 68 + c4 * 4]);
            __builtin_nontemporal_store(
                v, (f32x4*)&C[(size_t)(mrow_base + mi * 16 + row) * N +
                              ncol_base + c4 * 4]);
        }
        asm volatile("s_waitcnt lgkmcnt(0)" ::: "memory"); // reads done before overwrite
        __builtin_amdgcn_sched_barrier(0);
    }
}

// ---------- dual GEMM: z=0 QKV (N=1536), z=1 eKV (N=1024); BM=64,BN=128,K=512 ----------
struct DualArgs {
    const u16 *A0, *W0, *A1, *W1;
    const float *b00, *b01, *b02, *b10, *b11;
    u16 *C0, *C1;
};

__global__ __launch_bounds__(256) void gemm_dual_k(DualArgs da) {
    constexpr int BM = 64, BN = 128, MF = 2, NF = 4;
    constexpr int CH_A = BM * 4, CH_TOT = (BM + BN) * 4, L = CH_TOT / 256;
    __shared__ u16 sA[4][BM * 32];
    __shared__ u16 sB[4][BN * 32];

    const int z = blockIdx.z;
    const int gy = z ? 8 : 12;
    if ((int)blockIdx.y >= gy) return;
    const int N = z ? 1024 : 1536;
    const u16* A = z ? da.A1 : da.A0;
    const u16* W = z ? da.W1 : da.W0;
    u16* C = z ? da.C1 : da.C0;
    const int K = 512;

    const int gx = gridDim.x;                 // 64
    const int nwg = gx * gy;
    const int orig = blockIdx.y * gx + blockIdx.x;
    const int xcd = orig & 7, chnk = orig >> 3;
    const int q = nwg >> 3, r = nwg & 7;
    const int wgid = (xcd < r ? xcd * (q + 1) : r * (q + 1) + (xcd - r) * q) + chnk;
    const int m0 = (wgid % gx) * BM;
    const int n0 = (wgid / gx) * BN;

    const int tid  = threadIdx.x;
    const int lane = tid & 63;
    const int wid  = tid >> 6;
    const int wr = wid >> 1, wc = wid & 1;
    const int lg = lane >> 4, lr = lane & 15;

    f32x4 acc[MF][NF];
#pragma unroll
    for (int i = 0; i < MF; i++)
#pragma unroll
        for (int j = 0; j < NF; j++) acc[i][j] = (f32x4){0.f, 0.f, 0.f, 0.f};

    auto stage = [&](int b, int kt) {
        const int k0 = kt << 5;
#pragma unroll
        for (int h = 0; h < L; h++) {
            const int c = tid + h * 256;
            if (c < CH_A) {
                const int row = c >> 2, ch = c & 3;
                const int gch = ch ^ ((row >> 1) & 3);
                GLOAD_LDS16(A + (size_t)(m0 + row) * K + k0 + gch * 8,
                            &sA[b][c * 8]);
            } else {
                const int cb = c - CH_A;
                const int row = cb >> 2, ch = cb & 3;
                const int gch = ch ^ ((row >> 1) & 3);
                GLOAD_LDS16(W + (size_t)(n0 + row) * K + k0 + gch * 8,
                            &sB[b][cb * 8]);
            }
        }
    };

    const int NT = K >> 5;                    // 16
    stage(0, 0); stage(1, 1); stage(2, 2);

    for (int kt = 0; kt < NT; kt++) {
        wait_ring<L>(kt, NT);
        __builtin_amdgcn_s_barrier();
        const int bsel = kt & 3;
        if (kt + 3 < NT) stage((kt + 3) & 3, kt + 3);

        bf16x8 af[MF], bfr[NF];
#pragma unroll
        for (int mi = 0; mi < MF; mi++) {
            const int row = wr * (BM / 2) + mi * 16 + lr;
            af[mi] = *(const bf16x8*)(&sA[bsel][row * 32 + (lg ^ ((row >> 1) & 3)) * 8]);
        }
#pragma unroll
        for (int ni = 0; ni < NF; ni++) {
            const int row = wc * (BN / 2) + ni * 16 + lr;
            bfr[ni] = *(const bf16x8*)(&sB[bsel][row * 32 + (lg ^ ((row >> 1) & 3)) * 8]);
        }
        __builtin_amdgcn_s_setprio(1);
#pragma unroll
        for (int mi = 0; mi < MF; mi++)
#pragma unroll
            for (int ni = 0; ni < NF; ni++)
                acc[mi][ni] = mfma16(af[mi], bfr[ni], acc[mi][ni]);
        __builtin_amdgcn_s_setprio(0);
    }

#pragma unroll
    for (int mi = 0; mi < MF; mi++) {
        const int rbase = m0 + wr * (BM / 2) + mi * 16 + lg * 4;
#pragma unroll
        for (int ni = 0; ni < NF; ni++) {
            const int col = n0 + wc * (BN / 2) + ni * 16 + lr;
            const float* bp; int cc;
            if (z == 0) {
                if (col >= 1024)     { bp = da.b02; cc = col - 1024; }
                else if (col >= 512) { bp = da.b01; cc = col - 512; }
                else                 { bp = da.b00; cc = col; }
            } else {
                if (col >= 512)      { bp = da.b11; cc = col - 512; }
                else                 { bp = da.b10; cc = col; }
            }
            const float bv = bp[cc];
#pragma unroll
            for (int rr = 0; rr < 4; rr++)
                C[(size_t)(rbase + rr) * N + col] = f2b(acc[mi][ni][rr] + bv);
        }
    }
}

// ---------- V transpose (both attns in one launch): z selects src ----------
__global__ __launch_bounds__(256) void vt_k(const u16* __restrict__ V0, int rs0,
                                            u16* __restrict__ VT0,
                                            const u16* __restrict__ V1, int rs1,
                                            u16* __restrict__ VT1) {
    const u16* V = blockIdx.z ? V1 : V0;
    u16* VT = blockIdx.z ? VT1 : VT0;
    const int rs = blockIdx.z ? rs1 : rs0;
    const int bh = blockIdx.x;
    const int b = bh >> 3;
    const int h64 = (bh & 7) * 64;
    const int t0 = blockIdx.y * 64;
    __shared__ u16 s[64 * 65];
    const int tid = threadIdx.x;
#pragma unroll
    for (int i = 0; i < 16; i++) {
        int t = (tid >> 6) + i * 4;
        int d = tid & 63;
        s[d * 65 + t] = V[(size_t)(b * 1024 + t0 + t) * rs + h64 + d];
    }
    __syncthreads();
#pragma unroll
    for (int i = 0; i < 16; i++) {
        int d = (tid >> 6) + i * 4;
        int t = tid & 63;
        VT[(size_t)(bh * 64 + d) * 1024 + t0 + t] = s[d * 65 + t];
    }
}

// ---------- flash attention: 4-wave blocks (64 q-rows), K/V staged to LDS
// via global_load_lds double-buffer (ring-2), XOR-swizzled both sides. ----------
template <int CAUSAL>
__global__ __launch_bounds__(256) void attn_k(const u16* __restrict__ Q, int qrs,
                                              const u16* __restrict__ Kb, int krs,
                                              const u16* __restrict__ VT,
                                              const int* __restrict__ tokens,
                                              const signed char* __restrict__ km8,
                                              u16* __restrict__ O, int LK) {
    const int bh = blockIdx.x;
    const int b = bh >> 3;
    const int h64 = (bh & 7) * 64;
    const int qblk = blockIdx.y;               // 64 q-rows per block
    const int tid = threadIdx.x;
    const int wid = tid >> 6;
    const int lane = tid & 63;
    const int lg = lane >> 4, lr = lane & 15;
    const float NEG = -3.402823466e38f;

    __shared__ u16 sK[2][64 * 64];             // [key][d], chunk-swizzled
    __shared__ u16 sV[2][64 * 64];             // [d][key], chunk-swizzled
    __shared__ u16 sP[4][16 * 72];             // per-wave P exchange
    __shared__ int sFlag;

    const int q0 = qblk * 64 + wid * 16;
    const u16* qrow = Q + (size_t)(b * 1024 + q0 + lr) * qrs + h64 + lg * 8;
    const bf16x8 aq0 = *(const bf16x8*)(qrow);
    const bf16x8 aq1 = *(const bf16x8*)(qrow + 32);

    f32x4 o[4];
#pragma unroll
    for (int ni = 0; ni < 4; ni++) o[ni] = (f32x4){0.f, 0.f, 0.f, 0.f};
    float m_run[4], l_run[4];
#pragma unroll
    for (int rr = 0; rr < 4; rr++) { m_run[rr] = NEG; l_run[rr] = 0.f; }

    const u16* kbase = Kb + (size_t)b * LK * krs + h64;
    const u16* vbase = VT + (size_t)bh * 64 * LK;

    auto stage = [&](int buf, int k0) {
#pragma unroll
        for (int h = 0; h < 2; h++) {
            const int cidx = tid + h * 256;    // 512 chunks of 16B (K tile)
            const int rk = cidx >> 3, ch = cidx & 7;
            GLOAD_LDS16(kbase + (size_t)(k0 + rk) * krs + (ch ^ (rk & 7)) * 8,
                        &sK[buf][cidx * 8]);
        }
#pragma unroll
        for (int h = 0; h < 2; h++) {
            const int cidx = tid + h * 256;    // 512 chunks (V tile)
            const int dv = cidx >> 3, ch = cidx & 7;
            GLOAD_LDS16(vbase + (size_t)dv * LK + k0 + (ch ^ (dv & 7)) * 8,
                        &sV[buf][cidx * 8]);
        }
    };

    auto body = [&](int cur, int k0) {
        f32x4 s[4];
        __builtin_amdgcn_s_setprio(1);
#pragma unroll
        for (int c = 0; c < 4; c++) {
            const int rk = c * 16 + lr;
            bf16x8 bk0 = *(const bf16x8*)(&sK[cur][(rk * 8 + (lg ^ (rk & 7))) * 8]);
            bf16x8 bk1 =
                *(const bf16x8*)(&sK[cur][(rk * 8 + ((lg + 4) ^ (rk & 7))) * 8]);
            f32x4 t = (f32x4){0.f, 0.f, 0.f, 0.f};
            t = mfma16(aq0, bk0, t);
            t = mfma16(aq1, bk1, t);
            s[c] = t;
        }
        __builtin_amdgcn_s_setprio(0);
#pragma unroll
        for (int c = 0; c < 4; c++) {
            const int key = k0 + c * 16 + lr;
            bool mkey;
            if (CAUSAL) mkey = (tokens[b * LK + key] == 0);
            else        mkey = (km8[b * LK + key] != 0);
#pragma unroll
            for (int rr = 0; rr < 4; rr++) {
                float sv = s[c][rr] * 0.125f;   // 1/sqrt(64)
                bool mk = mkey;
                if (CAUSAL) mk = mk || (key > q0 + lg * 4 + rr);
                s[c][rr] = mk ? NEG : sv;
            }
        }
        float pf[4];
#pragma unroll
        for (int rr = 0; rr < 4; rr++) {
            float bm = fmaxf(fmaxf(s[0][rr], s[1][rr]), fmaxf(s[2][rr], s[3][rr]));
            bm = fmaxf(bm, __shfl_xor(bm, 1));
            bm = fmaxf(bm, __shfl_xor(bm, 2));
            bm = fmaxf(bm, __shfl_xor(bm, 4));
            bm = fmaxf(bm, __shfl_xor(bm, 8));
            float mn = fmaxf(m_run[rr], bm);
            float sc = __expf(m_run[rr] - mn);
            float p0 = __expf(s[0][rr] - mn);
            float p1 = __expf(s[1][rr] - mn);
            float p2 = __expf(s[2][rr] - mn);
            float p3 = __expf(s[3][rr] - mn);
            float bs = (p0 + p1) + (p2 + p3);
            bs += __shfl_xor(bs, 1);
            bs += __shfl_xor(bs, 2);
            bs += __shfl_xor(bs, 4);
            bs += __shfl_xor(bs, 8);
            l_run[rr] = l_run[rr] * sc + bs;
            m_run[rr] = mn;
            pf[rr] = sc;
            s[0][rr] = p0; s[1][rr] = p1; s[2][rr] = p2; s[3][rr] = p3;
        }
#pragma unroll
        for (int ni = 0; ni < 4; ni++)
#pragma unroll
            for (int rr = 0; rr < 4; rr++) o[ni][rr] *= pf[rr];
#pragma unroll
        for (int c = 0; c < 4; c++)
#pragma unroll
            for (int rr = 0; rr < 4; rr++)
                sP[wid][(lg * 4 + rr) * 72 + c * 16 + lr] = f2b(s[c][rr]);
        bf16x8 ap0 = *(const bf16x8*)(&sP[wid][lr * 72 + lg * 8]);
        bf16x8 ap1 = *(const bf16x8*)(&sP[wid][lr * 72 + 32 + lg * 8]);
        __builtin_amdgcn_s_setprio(1);
#pragma unroll
        for (int ni = 0; ni < 4; ni++) {
            const int rv = ni * 16 + lr;
            bf16x8 bv0 = *(const bf16x8*)(&sV[cur][(rv * 8 + (lg ^ (rv & 7))) * 8]);
            bf16x8 bv1 =
                *(const bf16x8*)(&sV[cur][(rv * 8 + ((lg + 4) ^ (rv & 7))) * 8]);
            o[ni] = mfma16(ap0, bv0, o[ni]);
            o[ni] = mfma16(ap1, bv1, o[ni]);
        }
        __builtin_amdgcn_s_setprio(0);
    };

    int kend = CAUSAL ? ((qblk + 1) << 6) : LK;
    if (kend > LK) kend = LK;
    const int nit = kend >> 6;
    stage(0, 0);
    for (int it = 0; it < nit; it++) {
        asm volatile("s_waitcnt vmcnt(0)" ::: "memory");
        __syncthreads();
        const int cur = it & 1;
        if (it + 1 < nit) stage(cur ^ 1, (it + 1) << 6);
        body(cur, it << 6);
    }
    if (CAUSAL && kend < LK) {
        bool fm = (m_run[0] == NEG) || (m_run[1] == NEG) ||
                  (m_run[2] == NEG) || (m_run[3] == NEG);
        if (tid == 0) sFlag = 0;
        __syncthreads();
        if (__any(fm) && lane == 0) sFlag = 1;
        __syncthreads();
        if (sFlag) {
            const int nit2 = LK >> 6;
            stage(nit & 1, nit << 6);
            for (int it = nit; it < nit2; it++) {
                asm volatile("s_waitcnt vmcnt(0)" ::: "memory");
                __syncthreads();
                const int cur = it & 1;
                if (it + 1 < nit2) stage(cur ^ 1, (it + 1) << 6);
                body(cur, it << 6);
            }
        }
    }

#pragma unroll
    for (int ni = 0; ni < 4; ni++)
#pragma unroll
        for (int rr = 0; rr < 4; rr++) {
            float v = o[ni][rr] / l_run[rr];
            O[(size_t)(b * 1024 + q0 + lg * 4 + rr) * 512 + h64 + ni * 16 + lr] =
                f2b(v);
        }
}

// ---------- fused residual + LayerNorm; writes f32 (opt) + bf16 ----------
__global__ __launch_bounds__(256) void ln_k(const float* __restrict__ a,
                                            const float* __restrict__ res,
                                            const float* __restrict__ g,
                                            const float* __restrict__ be,
                                            float* __restrict__ outf,
                                            u16* __restrict__ outb) {
    const int row = blockIdx.x;
    const int tid = threadIdx.x;
    const size_t base = (size_t)row * 512;
    float2 av = ((const float2*)(a + base))[tid];
    float2 rv = ((const float2*)(res + base))[tid];
    float x0 = av.x + rv.x;
    float x1 = av.y + rv.y;
    float s = x0 + x1, q = x0 * x0 + x1 * x1;
#pragma unroll
    for (int off = 1; off < 64; off <<= 1) {
        s += __shfl_xor(s, off);
        q += __shfl_xor(q, off);
    }
    __shared__ float ps[8];
    const int wid = tid >> 6;
    if ((tid & 63) == 0) { ps[wid] = s; ps[wid + 4] = q; }
    __syncthreads();
    s = ps[0] + ps[1] + ps[2] + ps[3];
    q = ps[4] + ps[5] + ps[6] + ps[7];
    const float mu = s * (1.f / 512.f);
    const float var = q * (1.f / 512.f) - mu * mu;
    const float inv = rsqrtf(var + 1e-5f);
    float2 gv = ((const float2*)g)[tid];
    float2 bv = ((const float2*)be)[tid];
    float y0 = gv.x * (x0 - mu) * inv + bv.x;
    float y1 = gv.y * (x1 - mu) * inv + bv.y;
    if (outf) { ((float2*)(outf + base))[tid] = make_float2(y0, y1); }
    outb[base + tid * 2] = f2b(y0);
    outb[base + tid * 2 + 1] = f2b(y1);
}

// ---------- host ----------
extern "C" void kernel_launch(void* const* d_in, const int* in_sizes, int n_in,
                              void* d_out, int out_size, void* d_ws, size_t ws_size,
                              hipStream_t stream) {
    (void)in_sizes; (void)n_in; (void)out_size;
    const int*   tokens  = (const int*)d_in[0];
    const float* enc     = (const float*)d_in[1];
    const signed char* encmask = (const signed char*)d_in[2];
    const float* emb     = (const float*)d_in[3];
    const float* Wq  = (const float*)d_in[4];  const float* bq  = (const float*)d_in[5];
    const float* Wk  = (const float*)d_in[6];  const float* bk  = (const float*)d_in[7];
    const float* Wv  = (const float*)d_in[8];  const float* bv  = (const float*)d_in[9];
    const float* Wo1 = (const float*)d_in[10]; const float* bo1 = (const float*)d_in[11];
    const float* cWq = (const float*)d_in[12]; const float* cbq = (const float*)d_in[13];
    const float* eWk = (const float*)d_in[14]; const float* ebk = (const float*)d_in[15];
    const float* eWv = (const float*)d_in[16]; const float* ebv = (const float*)d_in[17];
    const float* Wo2 = (const float*)d_in[18]; const float* bo2 = (const float*)d_in[19];
    const float* W1  = (const float*)d_in[20]; const float* b1  = (const float*)d_in[21];
    const float* W2  = (const float*)d_in[22]; const float* b2  = (const float*)d_in[23];
    const float* g1  = (const float*)d_in[24]; const float* be1 = (const float*)d_in[25];
    const float* g2  = (const float*)d_in[26]; const float* be2 = (const float*)d_in[27];
    const float* g3  = (const float*)d_in[28]; const float* be3 = (const float*)d_in[29];
    const float* Wout= (const float*)d_in[30]; const float* bout= (const float*)d_in[31];
    float* out = (float*)d_out;

    char* ws = (char*)d_ws;
    size_t off = 0;
    auto alloc = [&](size_t bytes) -> void* {
        void* p = ws + off;
        off += (bytes + 255) & ~(size_t)255;
        return p;
    };

    u16* Wqkvb = (u16*)alloc((size_t)786432 * 2);        // [1536,512]
    u16* Wo1b  = (u16*)alloc(262144 * 2);
    u16* cWqb  = (u16*)alloc(262144 * 2);
    u16* eWkvb = (u16*)alloc((size_t)524288 * 2);        // [1024,512]
    u16* Wo2b  = (u16*)alloc(262144 * 2);
    u16* W1b   = (u16*)alloc(524288 * 2);
    u16* W2b   = (u16*)alloc(524288 * 2);
    u16* Woutb = (u16*)alloc((size_t)16384000 * 2);
    u16* encb  = (u16*)alloc((size_t)2097152 * 2);
    float* x0f = (float*)alloc((size_t)2097152 * 4);
    u16*   x0b = (u16*)alloc((size_t)2097152 * 2);
    float* x1f = (float*)alloc((size_t)2097152 * 4);
    u16*   x1b = (u16*)alloc((size_t)2097152 * 2);
    float* x2f = (float*)alloc((size_t)2097152 * 4);
    u16*   x2b = (u16*)alloc((size_t)2097152 * 2);
    u16*   x3b = (u16*)alloc((size_t)2097152 * 2);
    u16* qkv = (u16*)alloc((size_t)4096 * 1536 * 2);     // fused q|k|v
    u16* ekv = (u16*)alloc((size_t)4096 * 1024 * 2);     // fused ek|ev
    u16* cq  = (u16*)alloc((size_t)2097152 * 2);
    u16* vt  = (u16*)alloc((size_t)2097152 * 2);         // self-attn VT
    u16* vt2 = (u16*)alloc((size_t)2097152 * 2);         // cross-attn VT
    u16* t4  = (u16*)alloc((size_t)2097152 * 2);         // attn out (reused)
    float* p8 = (float*)alloc((size_t)2097152 * 4);
    u16*  hb  = (u16*)alloc((size_t)4194304 * 2);        // relu hidden [4096,1024]
    if (off > ws_size) return;

    // fused embed + merged weight/enc casts (one launch)
    CastArgs ca;
    const float* srcs[12] = {Wq, Wk, Wv, Wo1, cWq, eWk, eWv, Wo2, W1, W2, enc, Wout};
    u16* dsts[12] = {Wqkvb, Wqkvb + 262144, Wqkvb + 524288, Wo1b, cWqb,
                     eWkvb, eWkvb + 262144, Wo2b, W1b, W2b, encb, Woutb};
    int ns[12] = {262144, 262144, 262144, 262144, 262144, 262144, 262144, 262144,
                  524288, 524288, 2097152, 16384000};
    int acc4 = 0;
    for (int j = 0; j < 12; j++) {
        ca.src[j] = (const float4*)srcs[j];
        ca.dst[j] = (ushort4*)dsts[j];
        ca.start4[j] = acc4;
        acc4 += ns[j] / 4;
    }
    ca.start4[12] = acc4;
    ca.tokens = tokens; ca.emb = emb; ca.xf = x0f; ca.xb = x0b;
    cast_embed_k<<<4096 + 4096, 256, 0, stream>>>(ca);

    // fused QKV (x0b) + eKV (encb) in ONE launch
    DualArgs da;
    da.A0 = x0b;  da.W0 = Wqkvb; da.A1 = encb; da.W1 = eWkvb;
    da.b00 = bq;  da.b01 = bk;   da.b02 = bv;
    da.b10 = ebk; da.b11 = ebv;
    da.C0 = qkv;  da.C1 = ekv;
    gemm_dual_k<<<dim3(64, 12, 2), 256, 0, stream>>>(da);

    // both V transposes, one launch
    vt_k<<<dim3(32, 16, 2), 256, 0, stream>>>(qkv + 1024, 1536, vt,
                                              ekv + 512, 1024, vt2);

    attn_k<1><<<dim3(32, 16), 256, 0, stream>>>(qkv, 1536, qkv + 512, 1536, vt,
                                                tokens, nullptr, t4, 1024);
    gemm_sm_k<64, 64><<<dim3(64, 8), 256, 0, stream>>>(
        t4, Wo1b, bo1, nullptr, nullptr, p8, nullptr, 4096, 512, 512, 0);
    ln_k<<<4096, 256, 0, stream>>>(p8, x0f, g1, be1, x1f, x1b);

    gemm_sm_k<64, 64><<<dim3(64, 8), 256, 0, stream>>>(
        x1b, cWqb, cbq, nullptr, nullptr, nullptr, cq, 4096, 512, 512, 0);
    attn_k<0><<<dim3(32, 16), 256, 0, stream>>>(cq, 512, ekv, 1024, vt2,
                                                nullptr, encmask, t4, 1024);
    gemm_sm_k<64, 64><<<dim3(64, 8), 256, 0, stream>>>(
        t4, Wo2b, bo2, nullptr, nullptr, p8, nullptr, 4096, 512, 512, 0);
    ln_k<<<4096, 256, 0, stream>>>(p8, x1f, g3, be3, x2f, x2b);

    // FFN
    gemm_sm_k<64, 128><<<dim3(64, 8), 256, 0, stream>>>(
        x2b, W1b, b1, nullptr, nullptr, nullptr, hb, 4096, 1024, 512, 1);
    gemm_sm_k<64, 64><<<dim3(64, 8), 256, 0, stream>>>(
        hb, W2b, b2, nullptr, nullptr, p8, nullptr, 4096, 512, 1024, 0);
    ln_k<<<4096, 256, 0, stream>>>(p8, x2f, g2, be2, nullptr, x3b);

    // vocab projection: 128x128 ring-2, m-fast 1-D grid, full-line NT stores
    gemm_wout_k<<<8000, 256, 0, stream>>>(x3b, Woutb, bout, out, 4096, 32000, 512);
}